// Round 4
// baseline (257.268 us; speedup 1.0000x reference)
//
#include <hip/hip_runtime.h>
#include <hip/hip_bf16.h>

typedef __hip_bfloat16 bf16;
typedef __attribute__((ext_vector_type(8))) short short8;   // 8 bf16 (4 VGPRs)
typedef __attribute__((ext_vector_type(4))) float f32x4;
typedef unsigned int uint32;

#define MFMA16(a, b, c) __builtin_amdgcn_mfma_f32_16x16x32_bf16(a, b, c, 0, 0, 0)

constexpr int EMB   = 1024;
constexpr int SEQ   = 2048;
constexpr int BATCH = 4;
constexpr int NH    = 16;
constexpr int HD    = 64;
constexpr int QKVW  = 3 * EMB;   // 3072, stride of fused QKV buffer
// softmax scale 1/sqrt(64) folded into Q projection, in log2 units
constexpr float QSCALE = 0.125f * 1.44269504f;

// async global->LDS, 16B per lane; LDS dest = wave-uniform base + lane*16
__device__ __forceinline__ void gl_lds16(const bf16* g, bf16* l) {
    __builtin_amdgcn_global_load_lds(
        (const __attribute__((address_space(1))) void*)g,
        (__attribute__((address_space(3))) void*)l,
        16, 0, 0);
}

__device__ __forceinline__ float fexp2(float x) {
#if __has_builtin(__builtin_amdgcn_exp2f)
    return __builtin_amdgcn_exp2f(x);   // single v_exp_f32
#else
    return exp2f(x);
#endif
}

// pack two f32 -> bf16x2 (round-half-up): add 0x8000, take high halves via perm.
// 3 VALU vs ~12-16 for two __float2bfloat16. a -> low half, b -> high half.
__device__ __forceinline__ uint32 pack2(float a, float b) {
    uint32 ua = __builtin_bit_cast(uint32, a) + 0x8000u;
    uint32 ub = __builtin_bit_cast(uint32, b) + 0x8000u;
    return __builtin_amdgcn_perm(ub, ua, 0x07060302u);  // {ub.hi16, ua.hi16}
}

__device__ __forceinline__ bf16 fbf16(float f) {        // fast scalar convert
    unsigned short u =
        (unsigned short)((__builtin_bit_cast(uint32, f) + 0x8000u) >> 16);
    return __builtin_bit_cast(bf16, u);
}

// Ps swizzle: logical 16 rows x 32 dwords, physical 4-dword block XORed with
// row&7. Returns bf16-element offset of dword `cd` in row `row`.
__device__ __forceinline__ int ps_dw(int row, int cd) {
    return row * 64 + ((((cd >> 2) ^ (row & 7)) << 3) + ((cd & 3) << 1));
}

// ---------------------------------------------------------------------------
// One fused conversion kernel: x -> xc, {Wq,Wk,Wv} -> Wqkv (row-concat),
// Wo -> Woc. 3072 blocks: [0,2048) x, then 4x256 for the weights.
// ---------------------------------------------------------------------------
__global__ void convert_all(const float* __restrict__ x,
                            const float* __restrict__ wq,
                            const float* __restrict__ wk,
                            const float* __restrict__ wv,
                            const float* __restrict__ wo,
                            bf16* __restrict__ xc,
                            bf16* __restrict__ wqkv,
                            bf16* __restrict__ woc) {
    const int NX = BATCH * SEQ * EMB;
    const int NW = EMB * EMB;
    const float* src; bf16* dst; int n4, b0, nb;
    const int blk = blockIdx.x;
    if (blk < 2048)      { src = x;  dst = xc;          n4 = NX / 4; b0 = 0;    nb = 2048; }
    else if (blk < 2304) { src = wq; dst = wqkv;        n4 = NW / 4; b0 = 2048; nb = 256; }
    else if (blk < 2560) { src = wk; dst = wqkv + NW;   n4 = NW / 4; b0 = 2304; nb = 256; }
    else if (blk < 2816) { src = wv; dst = wqkv + 2*NW; n4 = NW / 4; b0 = 2560; nb = 256; }
    else                 { src = wo; dst = woc;         n4 = NW / 4; b0 = 2816; nb = 256; }
    for (int i = (blk - b0) * 256 + threadIdx.x; i < n4; i += nb * 256) {
        float4 v = ((const float4*)src)[i];
        uint2 o;
        o.x = pack2(v.x, v.y);
        o.y = pack2(v.z, v.w);
        ((uint2*)dst)[i] = o;
    }
}

// ---------------------------------------------------------------------------
// GEMM: C[M,N] = A[M,K]*B[N,K]^T, scaled by `oscale` for col-blocks < qlim.
// 128x128 tile, BK=64, global_load_lds staging, XOR-swizzled LDS.
// 1D grid + XCD-chunk swizzle (T1).
// ---------------------------------------------------------------------------
template <typename OutT>
__global__ __launch_bounds__(256) void gemm_bt(const bf16* __restrict__ A,
                                               const bf16* __restrict__ B,
                                               OutT* __restrict__ C,
                                               int M, int N, int K,
                                               float oscale, int qlim) {
    __shared__ __align__(16) bf16 As[128 * 64];
    __shared__ __align__(16) bf16 Bs[128 * 64];

    const int t    = threadIdx.x;
    const int lane = t & 63;
    const int wid  = t >> 6;
    const int l16  = lane & 15;
    const int quad = lane >> 4;
    const int e    = l16 & 7;            // swizzle key for reads
    const int wm   = (wid >> 1) * 64;
    const int wn   = (wid & 1) * 64;

    // XCD-aware bijective chunk swizzle (perf-only; nwg % 8 == 0 guaranteed)
    const int nwg = (int)gridDim.x;
    const int cpx = nwg >> 3;                       // chunk per XCD
    const int wg  = ((int)blockIdx.x & 7) * cpx + ((int)blockIdx.x >> 3);
    const int gx  = N >> 7;                         // tiles along N
    const int m0  = (wg / gx) * 128;
    const int n0  = (wg % gx) * 128;
    const float sc = (n0 < qlim) ? oscale : 1.0f;

    f32x4 acc[4][4] = {};
    const int srow = lane >> 3;                    // 0..7
    const int scol = ((lane & 7) ^ srow) * 8;      // swizzled staging column

    for (int k0 = 0; k0 < K; k0 += 64) {
        #pragma unroll
        for (int it = 0; it < 4; ++it) {
            int rb = it * 32 + wid * 8;  // wave-uniform LDS row base
            gl_lds16(&A[(size_t)(m0 + rb + srow) * K + k0 + scol], &As[rb * 64]);
            gl_lds16(&B[(size_t)(n0 + rb + srow) * K + k0 + scol], &Bs[rb * 64]);
        }
        __syncthreads();
        #pragma unroll
        for (int ks = 0; ks < 64; ks += 32) {
            const int cb = (ks >> 3) + quad;       // col-block before swizzle
            short8 af[4], bfr[4];
            #pragma unroll
            for (int i = 0; i < 4; ++i)
                af[i] = *(const short8*)&As[(wm + i * 16 + l16) * 64 + ((cb ^ e) * 8)];
            #pragma unroll
            for (int j = 0; j < 4; ++j)
                bfr[j] = *(const short8*)&Bs[(wn + j * 16 + l16) * 64 + ((cb ^ e) * 8)];
            #pragma unroll
            for (int i = 0; i < 4; ++i)
                #pragma unroll
                for (int j = 0; j < 4; ++j)
                    acc[i][j] = MFMA16(af[i], bfr[j], acc[i][j]);
        }
        __syncthreads();
    }

    // C/D layout: col(n)=l16, row(m)=quad*4+reg  [m89/m91]
    #pragma unroll
    for (int i = 0; i < 4; ++i)
        #pragma unroll
        for (int j = 0; j < 4; ++j)
            #pragma unroll
            for (int r = 0; r < 4; ++r) {
                int row = m0 + wm + i * 16 + quad * 4 + r;
                int col = n0 + wn + j * 16 + l16;
                float v = acc[i][j][r] * sc;
                if constexpr (sizeof(OutT) == 2)
                    C[(size_t)row * N + col] = fbf16(v);
                else
                    C[(size_t)row * N + col] = (OutT)v;
            }
}

// ---------------------------------------------------------------------------
// V transpose out of fused QKV: QKV[b*S+s][2048 + h*64 + d] -> Vt[bh][d][s]
// ---------------------------------------------------------------------------
__global__ __launch_bounds__(256) void transpose_v(const bf16* __restrict__ QKV,
                                                   bf16* __restrict__ Vt) {
    __shared__ __align__(16) bf16 Ts[4096];   // 64x64, 16B-block XOR swizzle
    const int t  = threadIdx.x;
    const int st = blockIdx.x;
    const int bh = blockIdx.y;
    const int b  = bh >> 4, h = bh & 15;
    const int s0 = st * 64;

    const bf16* src = QKV + ((size_t)(b * SEQ + s0)) * QKVW + 2 * EMB + h * HD;
    {
        int r = t >> 3, cq = t & 7;
        #pragma unroll
        for (int it = 0; it < 2; ++it, r += 32) {
            uint4 v = *(const uint4*)&src[(size_t)r * QKVW + cq * 8];
            int blk = cq ^ (r >> 3);
            *(uint4*)&Ts[r * 64 + blk * 8] = v;
        }
    }
    __syncthreads();
    bf16* dst = Vt + (size_t)bh * HD * SEQ + s0;
    {
        int d = t >> 3;
        const int sq = t & 7;
        #pragma unroll
        for (int it = 0; it < 2; ++it, d += 32) {
            short8 ov;
            #pragma unroll
            for (int i = 0; i < 8; ++i) {
                int s = sq * 8 + i;
                ov[i] = (short)__bfloat16_as_ushort(
                    Ts[s * 64 + (((d >> 3) ^ sq) << 3) + (d & 7)]);
            }
            *(short8*)&dst[(size_t)d * SEQ + sq * 8] = ov;
        }
    }
}

// ---------------------------------------------------------------------------
// Flash attention (causal), S^T orientation, double-buffered staging with raw
// s_barrier + vmcnt(4) (prefetch stays in flight across the barrier).
// XOR-swizzled K/V/Ps LDS.
//
// R3: latency-bound diagnosis (R0 4blk/CU imbalanced = 80us; R1 2blk/CU
// balanced = 71us; R2 load-hoist = 79us REGRESSION -> serial-chain latency,
// not LDS BW, is the limit). This version gets BOTH balance and occupancy:
// 64-row q-tiles, 32 per bh, paired {qt, 31-qt} -> exactly 33 k-tile-units
// per block, 1024 blocks, 40960 B LDS -> 4 blocks/CU, whole grid co-resident,
// 16 waves/CU (VGPR roughly halves: one 16-row group per wave, no s-loop).
// Loads stay inline/interleaved with MFMA (R2 lesson). Staging doubles but is
// L2-side; HBM was at 8%.
//
// XCD chunk = 128 blocks = 8 bh -> per-XCD K/V working set 4 MB = its L2.
// ---------------------------------------------------------------------------
__global__ __launch_bounds__(256) void flash_attn(const bf16* __restrict__ QKV,
                                                  const bf16* __restrict__ Vt,
                                                  bf16* __restrict__ O) {
    __shared__ __align__(16) bf16 Ks[2][64 * 64];    // [buf][key][d] swizzled
    __shared__ __align__(16) bf16 VTs[2][64 * 64];   // [buf][d][key] swizzled
    __shared__ __align__(16) bf16 Ps[4][16 * 64];    // per-wave P^T, swizzled

    const int t    = threadIdx.x;
    const int lane = t & 63;
    const int w    = t >> 6;
    const int l16  = lane & 15;
    const int quad = lane >> 4;
    const int e    = l16 & 7;

    // XCD-chunk swizzle: lin -> (bh, pair), bh-major within each XCD chunk
    const int lin = (int)blockIdx.x;                 // 0..1023
    const int wg  = ((lin & 7) << 7) + (lin >> 3);   // chunk = 1024/8 = 128
    const int bh  = wg >> 4;                         // 0..63
    const int pr  = wg & 15;                         // pair id 0..15
    const int b   = bh >> 4, h = bh & 15;

    const bf16* Qp = QKV + (size_t)b * SEQ * QKVW + h * HD;
    const bf16* Kp = QKV + (size_t)b * SEQ * QKVW + EMB + h * HD;
    const bf16* Vp = Vt + (size_t)bh * HD * SEQ;
    bf16* Op = O + (size_t)b * SEQ * EMB + h * HD;

    const int srow = lane >> 3;
    const int scol = ((lane & 7) ^ srow) * 8;   // swizzled staging column

    auto stage = [&](int kt, int buf) {
        const int kbase = kt * 64;
        #pragma unroll
        for (int it = 0; it < 2; ++it) {
            int rb = it * 32 + w * 8;
            gl_lds16(&Kp[(size_t)(kbase + rb + srow) * QKVW + scol], &Ks[buf][rb * 64]);
            gl_lds16(&Vp[(size_t)(rb + srow) * SEQ + kbase + scol], &VTs[buf][rb * 64]);
        }
    };

    for (int pass = 0; pass < 2; ++pass) {
        const int qt = pass ? pr : 31 - pr;          // heavy q-tile first
        const int q0 = qt * 64;                      // 64-row q-tile
        const int wq0 = q0 + w * 16;                 // wave's 16 q-rows

        // Q fragments as B-operand: B[k=quad*8+i][n=l16] == Q[q=l16][d=quad*8+i]
        short8 bQ[2];
        {
            const size_t qr = (size_t)(wq0 + l16) * QKVW;
            bQ[0] = *(const short8*)&Qp[qr + quad * 8];
            bQ[1] = *(const short8*)&Qp[qr + 32 + quad * 8];
        }

        f32x4 o[4] = {};             // O^T[d][q] accumulators
        float lrow = 0.f;            // per-lane partial sum of p

        const int ntiles = qt + 1;               // k-tiles of 64 keys

        stage(0, 0);
        if (ntiles > 1) stage(1, 1);

        for (int kt = 0; kt < ntiles; ++kt) {
            const int cur = kt & 1;
            const int kbase = kt * 64;
            // wait own oldest DMA loads (this tile); leave prefetch in flight
            if (kt < ntiles - 1) __builtin_amdgcn_s_waitcnt(0x0F74);   // vmcnt(4)
            else                 __builtin_amdgcn_s_waitcnt(0x0F70);   // vmcnt(0)
            __builtin_amdgcn_s_barrier();

            // --- S^T = K Q^T: A=K-frag(m=key), B=Q-frag(n=query) ---
            f32x4 sa[4];
            #pragma unroll
            for (int j = 0; j < 4; ++j) {
                f32x4 acc = {};
                acc = MFMA16(*(const short8*)&Ks[cur][(j * 16 + l16) * 64 + ((quad ^ e) * 8)],
                             bQ[0], acc);
                acc = MFMA16(*(const short8*)&Ks[cur][(j * 16 + l16) * 64 + (((4 + quad) ^ e) * 8)],
                             bQ[1], acc);
                sa[j] = acc;   // col=query=l16, row=key=quad*4+reg (+16j)
            }

            // --- softmax: p = exp2(s), masked->0; accumulate per-lane l ---
            float lsum = 0.f;
            if (kbase + 63 > wq0) {                 // diagonal tile: apply mask
                #pragma unroll
                for (int j = 0; j < 4; ++j)
                    #pragma unroll
                    for (int pp = 0; pp < 2; ++pp) {
                        int kg = kbase + j * 16 + quad * 4 + 2 * pp;
                        float e0 = fexp2(sa[j][2 * pp]);
                        float e1 = fexp2(sa[j][2 * pp + 1]);
                        float p0 = (kg     <= wq0 + l16) ? e0 : 0.f;
                        float p1 = (kg + 1 <= wq0 + l16) ? e1 : 0.f;
                        lsum += p0 + p1;
                        *(uint32*)&Ps[w][ps_dw(l16, j * 8 + quad * 2 + pp)] = pack2(p0, p1);
                    }
            } else {
                #pragma unroll
                for (int j = 0; j < 4; ++j)
                    #pragma unroll
                    for (int pp = 0; pp < 2; ++pp) {
                        float p0 = fexp2(sa[j][2 * pp]);
                        float p1 = fexp2(sa[j][2 * pp + 1]);
                        lsum += p0 + p1;
                        *(uint32*)&Ps[w][ps_dw(l16, j * 8 + quad * 2 + pp)] = pack2(p0, p1);
                    }
            }
            lrow += lsum;

            // --- O^T += V^T P^T (Ps wave-private: lgkm-ordered, no barrier) ---
            #pragma unroll
            for (int ks = 0; ks < 2; ++ks) {
                short8 bP = *(const short8*)&Ps[w][l16 * 64 + (((ks * 4 + quad) ^ e) << 3)];
                #pragma unroll
                for (int dg = 0; dg < 4; ++dg)
                    o[dg] = MFMA16(
                        *(const short8*)&VTs[cur][(dg * 16 + l16) * 64 + (((ks * 4 + quad) ^ e) * 8)],
                        bP, o[dg]);
            }

            __builtin_amdgcn_s_barrier();            // all waves done with buf[cur]
            if (kt + 2 < ntiles) stage(kt + 2, cur); // prefetch into freed buffer
        }

        // --- epilogue: reduce l across quads, scale, transpose via LDS, store ---
        {
            float l = lrow;
            l += __shfl_xor(l, 16);
            l += __shfl_xor(l, 32);
            float rl = 1.0f / l;
            #pragma unroll
            for (int dg = 0; dg < 4; ++dg)
                #pragma unroll
                for (int pp = 0; pp < 2; ++pp) {
                    float v0 = o[dg][2 * pp] * rl;
                    float v1 = o[dg][2 * pp + 1] * rl;
                    *(uint32*)&Ps[w][ps_dw(l16, dg * 8 + quad * 2 + pp)] = pack2(v0, v1);
                }
            // wave-private readback (rows=query, cols=d), coalesced global store
            #pragma unroll
            for (int it = 0; it < 2; ++it) {
                int qr = lane >> 2;
                int ch = (lane & 3) + 4 * it;
                short8 vv = *(const short8*)&Ps[w][qr * 64 + ((ch ^ (qr & 7)) << 3)];
                *(short8*)&Op[(size_t)(wq0 + qr) * EMB + ch * 8] = vv;
            }
        }
    }
}

// ---------------------------------------------------------------------------
extern "C" void kernel_launch(void* const* d_in, const int* in_sizes, int n_in,
                              void* d_out, int out_size, void* d_ws, size_t ws_size,
                              hipStream_t stream) {
    const float* x  = (const float*)d_in[0];
    const float* Wq = (const float*)d_in[1];
    const float* Wk = (const float*)d_in[2];
    const float* Wv = (const float*)d_in[3];
    const float* Wo = (const float*)d_in[4];
    float* out = (float*)d_out;            // reference output dtype: float32
    bf16*  ws  = (bf16*)d_ws;

    const int M  = BATCH * SEQ;            // 8192
    const int NX = M * EMB;                // 8388608
    const int NW = EMB * EMB;              // 1048576

    // workspace (bf16 elems), total 92,274,688 B (fits: proven R4-R7)
    bf16* xc   = ws;                       // [8192][1024]; dead after QKV GEMM
    bf16* Ab   = xc;                       // attention out aliases xc
    bf16* Wqkv = ws + (size_t)NX;          // [3072][1024] fused weights
    bf16* Woc  = Wqkv + 3 * (size_t)NW;
    bf16* QKV  = Woc + NW;                 // [8192][3072]
    bf16* Vt   = QKV + (size_t)M * QKVW;   // [64 bh][64 d][2048 s]

    // 1) one fused conversion launch
    convert_all<<<3072, 256, 0, stream>>>(x, Wq, Wk, Wv, Wo, xc, Wqkv, Woc);

    // 2) fused QKV projection (Q cols pre-scaled by QSCALE), XCD-swizzled 1D grid
    gemm_bt<bf16><<<dim3((QKVW / 128) * (M / 128)), 256, 0, stream>>>(
        xc, Wqkv, QKV, M, QKVW, EMB, QSCALE, EMB);

    // 3) V transpose into [bh][d][s]
    transpose_v<<<dim3(SEQ / 64, BATCH * NH), 256, 0, stream>>>(QKV, Vt);

    // 4) causal flash attention: 1024 uniform-work blocks (paired 64-row
    //    q-tiles, 4 blocks/CU co-resident), XCD-swizzled 1D grid
    flash_attn<<<dim3((SEQ / 64 / 2) * BATCH * NH), 256, 0, stream>>>(QKV, Vt, Ab);

    // 5) output projection -> fp32, XCD-swizzled 1D grid
    gemm_bt<float><<<dim3((EMB / 128) * (M / 128)), 256, 0, stream>>>(
        Ab, Woc, out, M, EMB, EMB, 1.0f, 0);
}

// Round 5
// 237.866 us; speedup vs baseline: 1.0816x; 1.0816x over previous
//
#include <hip/hip_runtime.h>
#include <hip/hip_bf16.h>

typedef __hip_bfloat16 bf16;
typedef __attribute__((ext_vector_type(8))) short short8;   // 8 bf16 (4 VGPRs)
typedef __attribute__((ext_vector_type(4))) float f32x4;
typedef unsigned int uint32;

#define MFMA16(a, b, c) __builtin_amdgcn_mfma_f32_16x16x32_bf16(a, b, c, 0, 0, 0)

constexpr int EMB   = 1024;
constexpr int SEQ   = 2048;
constexpr int BATCH = 4;
constexpr int NH    = 16;
constexpr int HD    = 64;
constexpr int QKVW  = 3 * EMB;   // 3072, stride of fused QKV buffer
// softmax scale 1/sqrt(64) folded into Q projection, in log2 units
constexpr float QSCALE = 0.125f * 1.44269504f;

// async global->LDS, 16B per lane; LDS dest = wave-uniform base + lane*16
__device__ __forceinline__ void gl_lds16(const bf16* g, bf16* l) {
    __builtin_amdgcn_global_load_lds(
        (const __attribute__((address_space(1))) void*)g,
        (__attribute__((address_space(3))) void*)l,
        16, 0, 0);
}

__device__ __forceinline__ float fexp2(float x) {
#if __has_builtin(__builtin_amdgcn_exp2f)
    return __builtin_amdgcn_exp2f(x);   // single v_exp_f32
#else
    return exp2f(x);
#endif
}

// pack two f32 -> bf16x2 (round-half-up): add 0x8000, take high halves via perm.
// 3 VALU vs ~12-16 for two __float2bfloat16. a -> low half, b -> high half.
__device__ __forceinline__ uint32 pack2(float a, float b) {
    uint32 ua = __builtin_bit_cast(uint32, a) + 0x8000u;
    uint32 ub = __builtin_bit_cast(uint32, b) + 0x8000u;
    return __builtin_amdgcn_perm(ub, ua, 0x07060302u);  // {ub.hi16, ua.hi16}
}

__device__ __forceinline__ bf16 fbf16(float f) {        // fast scalar convert
    unsigned short u =
        (unsigned short)((__builtin_bit_cast(uint32, f) + 0x8000u) >> 16);
    return __builtin_bit_cast(bf16, u);
}

// Ps swizzle: logical 16 rows x 32 dwords, physical 4-dword block XORed with
// row&7. Returns bf16-element offset of dword `cd` in row `row`.
__device__ __forceinline__ int ps_dw(int row, int cd) {
    return row * 64 + ((((cd >> 2) ^ (row & 7)) << 3) + ((cd & 3) << 1));
}

// ---------------------------------------------------------------------------
// One fused conversion kernel: x -> xc, {Wq,Wk,Wv} -> Wqkv (row-concat),
// Wo -> Woc. 3072 blocks: [0,2048) x, then 4x256 for the weights.
// ---------------------------------------------------------------------------
__global__ void convert_all(const float* __restrict__ x,
                            const float* __restrict__ wq,
                            const float* __restrict__ wk,
                            const float* __restrict__ wv,
                            const float* __restrict__ wo,
                            bf16* __restrict__ xc,
                            bf16* __restrict__ wqkv,
                            bf16* __restrict__ woc) {
    const int NX = BATCH * SEQ * EMB;
    const int NW = EMB * EMB;
    const float* src; bf16* dst; int n4, b0, nb;
    const int blk = blockIdx.x;
    if (blk < 2048)      { src = x;  dst = xc;          n4 = NX / 4; b0 = 0;    nb = 2048; }
    else if (blk < 2304) { src = wq; dst = wqkv;        n4 = NW / 4; b0 = 2048; nb = 256; }
    else if (blk < 2560) { src = wk; dst = wqkv + NW;   n4 = NW / 4; b0 = 2304; nb = 256; }
    else if (blk < 2816) { src = wv; dst = wqkv + 2*NW; n4 = NW / 4; b0 = 2560; nb = 256; }
    else                 { src = wo; dst = woc;         n4 = NW / 4; b0 = 2816; nb = 256; }
    for (int i = (blk - b0) * 256 + threadIdx.x; i < n4; i += nb * 256) {
        float4 v = ((const float4*)src)[i];
        uint2 o;
        o.x = pack2(v.x, v.y);
        o.y = pack2(v.z, v.w);
        ((uint2*)dst)[i] = o;
    }
}

// ---------------------------------------------------------------------------
// GEMM: C[M,N] = A[M,K]*B[N,K]^T, scaled by `oscale` for col-blocks < qlim.
// 128x128 tile, BK=64, global_load_lds staging, XOR-swizzled LDS.
//
// R4a: double-buffered staging with raw s_barrier + counted vmcnt(8) — the
// pipeline proven correct in flash_attn (per-wave vmcnt-then-barrier gives
// cross-wave completion; prefetch for tile kt+1 stays in flight across the
// compute of tile kt). Replaces the vmcnt(0)-draining __syncthreads pair.
//
// R4b: XCD chunk ordering column-major (m-fastest). Previous n-fastest order
// made the per-XCD resident window span all 24 B-panels (6 MB > 4 MB L2) ->
// FETCH_SIZE 85 MB (4x ideal). m-fastest window = 8 M-tiles x ~8 N-cols =
// A 2 MB + B 2 MB = 4 MB = exactly one L2.
// Requires gridDim.x % 8 == 0 and (gridDim.x/8) % (N/128) == 0 (1536, 512 ok).
// ---------------------------------------------------------------------------
template <typename OutT>
__global__ __launch_bounds__(256) void gemm_bt(const bf16* __restrict__ A,
                                               const bf16* __restrict__ B,
                                               OutT* __restrict__ C,
                                               int M, int N, int K,
                                               float oscale, int qlim) {
    __shared__ __align__(16) bf16 As[2][128 * 64];
    __shared__ __align__(16) bf16 Bs[2][128 * 64];

    const int t    = threadIdx.x;
    const int lane = t & 63;
    const int wid  = t >> 6;
    const int l16  = lane & 15;
    const int quad = lane >> 4;
    const int e    = l16 & 7;            // swizzle key for reads
    const int wm   = (wid >> 1) * 64;
    const int wn   = (wid & 1) * 64;

    // XCD-aware chunk swizzle, column-major (m-fastest) within chunk
    const int nwg   = (int)gridDim.x;
    const int cpx   = nwg >> 3;                     // blocks per XCD chunk
    const int gx    = N >> 7;                       // tiles along N
    const int mrows = cpx / gx;                     // M-tile rows per chunk
    const int xcd   = (int)blockIdx.x & 7;
    const int local = (int)blockIdx.x >> 3;         // 0..cpx-1
    const int m0    = (xcd * mrows + (local % mrows)) * 128;
    const int n0    = (local / mrows) * 128;
    const float sc  = (n0 < qlim) ? oscale : 1.0f;

    f32x4 acc[4][4] = {};
    const int srow = lane >> 3;                    // 0..7
    const int scol = ((lane & 7) ^ srow) * 8;      // swizzled staging column

    auto stage = [&](int kt, int buf) {
        const int k0 = kt * 64;
        #pragma unroll
        for (int it = 0; it < 4; ++it) {
            int rb = it * 32 + wid * 8;  // wave-uniform LDS row base
            gl_lds16(&A[(size_t)(m0 + rb + srow) * K + k0 + scol], &As[buf][rb * 64]);
            gl_lds16(&B[(size_t)(n0 + rb + srow) * K + k0 + scol], &Bs[buf][rb * 64]);
        }
    };

    const int nk = K >> 6;                         // 16 for K=1024
    stage(0, 0);
    stage(1, 1);

    for (int kt = 0; kt < nk; ++kt) {
        const int cur = kt & 1;
        // wait own oldest 8 DMA loads (this tile); leave prefetch in flight
        if (kt < nk - 1) __builtin_amdgcn_s_waitcnt(0x0F78);   // vmcnt(8)
        else             __builtin_amdgcn_s_waitcnt(0x0F70);   // vmcnt(0)
        __builtin_amdgcn_s_barrier();

        #pragma unroll
        for (int ks = 0; ks < 64; ks += 32) {
            const int cb = (ks >> 3) + quad;       // col-block before swizzle
            short8 af[4], bfr[4];
            #pragma unroll
            for (int i = 0; i < 4; ++i)
                af[i] = *(const short8*)&As[cur][(wm + i * 16 + l16) * 64 + ((cb ^ e) * 8)];
            #pragma unroll
            for (int j = 0; j < 4; ++j)
                bfr[j] = *(const short8*)&Bs[cur][(wn + j * 16 + l16) * 64 + ((cb ^ e) * 8)];
            #pragma unroll
            for (int i = 0; i < 4; ++i)
                #pragma unroll
                for (int j = 0; j < 4; ++j)
                    acc[i][j] = MFMA16(af[i], bfr[j], acc[i][j]);
        }

        __builtin_amdgcn_s_barrier();              // all waves done with buf[cur]
        if (kt + 2 < nk) stage(kt + 2, cur);       // prefetch into freed buffer
    }

    // C/D layout: col(n)=l16, row(m)=quad*4+reg  [m89/m91]
    #pragma unroll
    for (int i = 0; i < 4; ++i)
        #pragma unroll
        for (int j = 0; j < 4; ++j)
            #pragma unroll
            for (int r = 0; r < 4; ++r) {
                int row = m0 + wm + i * 16 + quad * 4 + r;
                int col = n0 + wn + j * 16 + l16;
                float v = acc[i][j][r] * sc;
                if constexpr (sizeof(OutT) == 2)
                    C[(size_t)row * N + col] = fbf16(v);
                else
                    C[(size_t)row * N + col] = (OutT)v;
            }
}

// ---------------------------------------------------------------------------
// V transpose out of fused QKV: QKV[b*S+s][2048 + h*64 + d] -> Vt[bh][d][s]
// ---------------------------------------------------------------------------
__global__ __launch_bounds__(256) void transpose_v(const bf16* __restrict__ QKV,
                                                   bf16* __restrict__ Vt) {
    __shared__ __align__(16) bf16 Ts[4096];   // 64x64, 16B-block XOR swizzle
    const int t  = threadIdx.x;
    const int st = blockIdx.x;
    const int bh = blockIdx.y;
    const int b  = bh >> 4, h = bh & 15;
    const int s0 = st * 64;

    const bf16* src = QKV + ((size_t)(b * SEQ + s0)) * QKVW + 2 * EMB + h * HD;
    {
        int r = t >> 3, cq = t & 7;
        #pragma unroll
        for (int it = 0; it < 2; ++it, r += 32) {
            uint4 v = *(const uint4*)&src[(size_t)r * QKVW + cq * 8];
            int blk = cq ^ (r >> 3);
            *(uint4*)&Ts[r * 64 + blk * 8] = v;
        }
    }
    __syncthreads();
    bf16* dst = Vt + (size_t)bh * HD * SEQ + s0;
    {
        int d = t >> 3;
        const int sq = t & 7;
        #pragma unroll
        for (int it = 0; it < 2; ++it, d += 32) {
            short8 ov;
            #pragma unroll
            for (int i = 0; i < 8; ++i) {
                int s = sq * 8 + i;
                ov[i] = (short)__bfloat16_as_ushort(
                    Ts[s * 64 + (((d >> 3) ^ sq) << 3) + (d & 7)]);
            }
            *(short8*)&dst[(size_t)d * SEQ + sq * 8] = ov;
        }
    }
}

// ---------------------------------------------------------------------------
// Flash attention (causal), S^T orientation, double-buffered staging with raw
// s_barrier + vmcnt(4) (prefetch stays in flight across the barrier).
// XOR-swizzled K/V/Ps LDS.
//
// R3: 64-row q-tiles, 32 per bh, paired {qt, 31-qt} -> 33 k-tile-units per
// block, 1024 blocks, 4 blocks/CU co-resident, balanced. (R4 counters:
// 68.8us, VALUBusy 45% top pipe - exp2-heavy softmax chain is the local
// floor of this structure; left unchanged this round.)
//
// XCD chunk = 128 blocks = 8 bh -> per-XCD K/V working set 4 MB = its L2.
// ---------------------------------------------------------------------------
__global__ __launch_bounds__(256) void flash_attn(const bf16* __restrict__ QKV,
                                                  const bf16* __restrict__ Vt,
                                                  bf16* __restrict__ O) {
    __shared__ __align__(16) bf16 Ks[2][64 * 64];    // [buf][key][d] swizzled
    __shared__ __align__(16) bf16 VTs[2][64 * 64];   // [buf][d][key] swizzled
    __shared__ __align__(16) bf16 Ps[4][16 * 64];    // per-wave P^T, swizzled

    const int t    = threadIdx.x;
    const int lane = t & 63;
    const int w    = t >> 6;
    const int l16  = lane & 15;
    const int quad = lane >> 4;
    const int e    = l16 & 7;

    // XCD-chunk swizzle: lin -> (bh, pair), bh-major within each XCD chunk
    const int lin = (int)blockIdx.x;                 // 0..1023
    const int wg  = ((lin & 7) << 7) + (lin >> 3);   // chunk = 1024/8 = 128
    const int bh  = wg >> 4;                         // 0..63
    const int pr  = wg & 15;                         // pair id 0..15
    const int b   = bh >> 4, h = bh & 15;

    const bf16* Qp = QKV + (size_t)b * SEQ * QKVW + h * HD;
    const bf16* Kp = QKV + (size_t)b * SEQ * QKVW + EMB + h * HD;
    const bf16* Vp = Vt + (size_t)bh * HD * SEQ;
    bf16* Op = O + (size_t)b * SEQ * EMB + h * HD;

    const int srow = lane >> 3;
    const int scol = ((lane & 7) ^ srow) * 8;   // swizzled staging column

    auto stage = [&](int kt, int buf) {
        const int kbase = kt * 64;
        #pragma unroll
        for (int it = 0; it < 2; ++it) {
            int rb = it * 32 + w * 8;
            gl_lds16(&Kp[(size_t)(kbase + rb + srow) * QKVW + scol], &Ks[buf][rb * 64]);
            gl_lds16(&Vp[(size_t)(rb + srow) * SEQ + kbase + scol], &VTs[buf][rb * 64]);
        }
    };

    for (int pass = 0; pass < 2; ++pass) {
        const int qt = pass ? pr : 31 - pr;          // heavy q-tile first
        const int q0 = qt * 64;                      // 64-row q-tile
        const int wq0 = q0 + w * 16;                 // wave's 16 q-rows

        // Q fragments as B-operand: B[k=quad*8+i][n=l16] == Q[q=l16][d=quad*8+i]
        short8 bQ[2];
        {
            const size_t qr = (size_t)(wq0 + l16) * QKVW;
            bQ[0] = *(const short8*)&Qp[qr + quad * 8];
            bQ[1] = *(const short8*)&Qp[qr + 32 + quad * 8];
        }

        f32x4 o[4] = {};             // O^T[d][q] accumulators
        float lrow = 0.f;            // per-lane partial sum of p

        const int ntiles = qt + 1;               // k-tiles of 64 keys

        stage(0, 0);
        if (ntiles > 1) stage(1, 1);

        for (int kt = 0; kt < ntiles; ++kt) {
            const int cur = kt & 1;
            const int kbase = kt * 64;
            // wait own oldest DMA loads (this tile); leave prefetch in flight
            if (kt < ntiles - 1) __builtin_amdgcn_s_waitcnt(0x0F74);   // vmcnt(4)
            else                 __builtin_amdgcn_s_waitcnt(0x0F70);   // vmcnt(0)
            __builtin_amdgcn_s_barrier();

            // --- S^T = K Q^T: A=K-frag(m=key), B=Q-frag(n=query) ---
            f32x4 sa[4];
            #pragma unroll
            for (int j = 0; j < 4; ++j) {
                f32x4 acc = {};
                acc = MFMA16(*(const short8*)&Ks[cur][(j * 16 + l16) * 64 + ((quad ^ e) * 8)],
                             bQ[0], acc);
                acc = MFMA16(*(const short8*)&Ks[cur][(j * 16 + l16) * 64 + (((4 + quad) ^ e) * 8)],
                             bQ[1], acc);
                sa[j] = acc;   // col=query=l16, row=key=quad*4+reg (+16j)
            }

            // --- softmax: p = exp2(s), masked->0; accumulate per-lane l ---
            float lsum = 0.f;
            if (kbase + 63 > wq0) {                 // diagonal tile: apply mask
                #pragma unroll
                for (int j = 0; j < 4; ++j)
                    #pragma unroll
                    for (int pp = 0; pp < 2; ++pp) {
                        int kg = kbase + j * 16 + quad * 4 + 2 * pp;
                        float e0 = fexp2(sa[j][2 * pp]);
                        float e1 = fexp2(sa[j][2 * pp + 1]);
                        float p0 = (kg     <= wq0 + l16) ? e0 : 0.f;
                        float p1 = (kg + 1 <= wq0 + l16) ? e1 : 0.f;
                        lsum += p0 + p1;
                        *(uint32*)&Ps[w][ps_dw(l16, j * 8 + quad * 2 + pp)] = pack2(p0, p1);
                    }
            } else {
                #pragma unroll
                for (int j = 0; j < 4; ++j)
                    #pragma unroll
                    for (int pp = 0; pp < 2; ++pp) {
                        float p0 = fexp2(sa[j][2 * pp]);
                        float p1 = fexp2(sa[j][2 * pp + 1]);
                        lsum += p0 + p1;
                        *(uint32*)&Ps[w][ps_dw(l16, j * 8 + quad * 2 + pp)] = pack2(p0, p1);
                    }
            }
            lrow += lsum;

            // --- O^T += V^T P^T (Ps wave-private: lgkm-ordered, no barrier) ---
            #pragma unroll
            for (int ks = 0; ks < 2; ++ks) {
                short8 bP = *(const short8*)&Ps[w][l16 * 64 + (((ks * 4 + quad) ^ e) << 3)];
                #pragma unroll
                for (int dg = 0; dg < 4; ++dg)
                    o[dg] = MFMA16(
                        *(const short8*)&VTs[cur][(dg * 16 + l16) * 64 + (((ks * 4 + quad) ^ e) * 8)],
                        bP, o[dg]);
            }

            __builtin_amdgcn_s_barrier();            // all waves done with buf[cur]
            if (kt + 2 < ntiles) stage(kt + 2, cur); // prefetch into freed buffer
        }

        // --- epilogue: reduce l across quads, scale, transpose via LDS, store ---
        {
            float l = lrow;
            l += __shfl_xor(l, 16);
            l += __shfl_xor(l, 32);
            float rl = 1.0f / l;
            #pragma unroll
            for (int dg = 0; dg < 4; ++dg)
                #pragma unroll
                for (int pp = 0; pp < 2; ++pp) {
                    float v0 = o[dg][2 * pp] * rl;
                    float v1 = o[dg][2 * pp + 1] * rl;
                    *(uint32*)&Ps[w][ps_dw(l16, dg * 8 + quad * 2 + pp)] = pack2(v0, v1);
                }
            // wave-private readback (rows=query, cols=d), coalesced global store
            #pragma unroll
            for (int it = 0; it < 2; ++it) {
                int qr = lane >> 2;
                int ch = (lane & 3) + 4 * it;
                short8 vv = *(const short8*)&Ps[w][qr * 64 + ((ch ^ (qr & 7)) << 3)];
                *(short8*)&Op[(size_t)(wq0 + qr) * EMB + ch * 8] = vv;
            }
        }
    }
}

// ---------------------------------------------------------------------------
extern "C" void kernel_launch(void* const* d_in, const int* in_sizes, int n_in,
                              void* d_out, int out_size, void* d_ws, size_t ws_size,
                              hipStream_t stream) {
    const float* x  = (const float*)d_in[0];
    const float* Wq = (const float*)d_in[1];
    const float* Wk = (const float*)d_in[2];
    const float* Wv = (const float*)d_in[3];
    const float* Wo = (const float*)d_in[4];
    float* out = (float*)d_out;            // reference output dtype: float32
    bf16*  ws  = (bf16*)d_ws;

    const int M  = BATCH * SEQ;            // 8192
    const int NX = M * EMB;                // 8388608
    const int NW = EMB * EMB;              // 1048576

    // workspace (bf16 elems), total 92,274,688 B (fits: proven R4-R7)
    bf16* xc   = ws;                       // [8192][1024]; dead after QKV GEMM
    bf16* Ab   = xc;                       // attention out aliases xc
    bf16* Wqkv = ws + (size_t)NX;          // [3072][1024] fused weights
    bf16* Woc  = Wqkv + 3 * (size_t)NW;
    bf16* QKV  = Woc + NW;                 // [8192][3072]
    bf16* Vt   = QKV + (size_t)M * QKVW;   // [64 bh][64 d][2048 s]

    // 1) one fused conversion launch
    convert_all<<<3072, 256, 0, stream>>>(x, Wq, Wk, Wv, Wo, xc, Wqkv, Woc);

    // 2) fused QKV projection (Q cols pre-scaled by QSCALE), XCD-swizzled 1D grid
    gemm_bt<bf16><<<dim3((QKVW / 128) * (M / 128)), 256, 0, stream>>>(
        xc, Wqkv, QKV, M, QKVW, EMB, QSCALE, EMB);

    // 3) V transpose into [bh][d][s]
    transpose_v<<<dim3(SEQ / 64, BATCH * NH), 256, 0, stream>>>(QKV, Vt);

    // 4) causal flash attention: 1024 uniform-work blocks (paired 64-row
    //    q-tiles, 4 blocks/CU co-resident), XCD-swizzled 1D grid
    flash_attn<<<dim3((SEQ / 64 / 2) * BATCH * NH), 256, 0, stream>>>(QKV, Vt, Ab);

    // 5) output projection -> fp32, XCD-swizzled 1D grid
    gemm_bt<float><<<dim3((EMB / 128) * (M / 128)), 256, 0, stream>>>(
        Ab, Woc, out, M, EMB, EMB, 1.0f, 0);
}